// Round 2
// baseline (754.093 us; speedup 1.0000x reference)
//
#include <hip/hip_runtime.h>
#include <hip/hip_bf16.h>
#include <math.h>

#define NHEADS 10

// ---------------- CSR build ----------------
__global__ void k_count(const int* eidx, int E, int N, int* cnt){
    int e = blockIdx.x*blockDim.x + threadIdx.x;
    int ET = E + N;
    if(e >= ET) return;
    int d = (e < E) ? eidx[E + e] : (e - E);
    atomicAdd(&cnt[d], 1);
}

__global__ void k_scan(int* cnt, int N, int ET, int* indptr){
    __shared__ int lds[1024];
    int t = threadIdx.x;
    int chunk = (N + 1023)/1024;
    int base = t*chunk;
    int s = 0;
    for(int i=0;i<chunk;i++){ int idx=base+i; if(idx<N) s += cnt[idx]; }
    lds[t]=s;
    __syncthreads();
    for(int off=1; off<1024; off<<=1){
        int v = (t>=off)? lds[t-off] : 0;
        __syncthreads();
        lds[t]+=v;
        __syncthreads();
    }
    int run = lds[t]-s;   // exclusive prefix of this thread's chunk
    for(int i=0;i<chunk;i++){
        int idx=base+i;
        if(idx<N){
            int c = cnt[idx];
            indptr[idx]=run;
            cnt[idx]=run;      // becomes cursor for fill
            run += c;
        }
    }
    if(t==0) indptr[N]=ET;
}

__global__ void k_fill(const int* eidx, int E, int N, int* cursor, int* srcs){
    int e = blockIdx.x*blockDim.x + threadIdx.x;
    int ET = E + N;
    if(e >= ET) return;
    int s, d;
    if(e < E){ s = eidx[e]; d = eidx[E+e]; } else { s = e-E; d = e-E; }
    int pos = atomicAdd(&cursor[d], 1);
    srcs[pos] = s;
}

// ---------------- fc0: [N,24]@[24,16]+b, ELU ----------------
__global__ void k_fc0(const float* x, const float* W0, const float* b0, float* out, int N){
    int idx = blockIdx.x*blockDim.x+threadIdx.x;
    if(idx >= N*16) return;
    int n = idx>>4, c = idx&15;
    float acc = b0[c];
    #pragma unroll
    for(int k=0;k<24;k++) acc += x[n*24+k] * W0[k*16+c];
    out[idx] = acc>0.f ? acc : expm1f(acc);
}

// ---------------- feature GEMM: hf[n, H*C] = hin[n,:] @ Wc ----------------
template<int FIN, int HC>
__global__ void k_feat(const float* hin, const float* Wc, float* hf, int N){
    __shared__ float row[FIN];
    int n = blockIdx.x;
    int t = threadIdx.x;
    if(t < FIN) row[t] = hin[n*FIN + t];
    __syncthreads();
    for(int col=t; col<HC; col+=256){
        float acc=0.f;
        #pragma unroll
        for(int k=0;k<FIN;k++) acc += row[k]*Wc[k*HC+col];
        hf[(size_t)n*HC+col] = acc;
    }
}

// ---------------- attention logits per (n,h) ----------------
template<int C>
__global__ void k_attn(const float* hf, const float* a_s, const float* a_d,
                       float* es, float* ed, int N){
    int idx = blockIdx.x*blockDim.x+threadIdx.x;
    if(idx >= N*NHEADS) return;
    int n = idx/NHEADS, h = idx%NHEADS;
    const float* hp = hf + (size_t)n*NHEADS*C + h*C;
    float s=0.f, d=0.f;
    for(int c=0;c<C;c++){
        float v = hp[c];
        s += v*a_s[h*C+c];
        d += v*a_d[h*C+c];
    }
    es[idx]=s; ed[idx]=d;
}

// ---------------- softmax stats + normalized per-edge weights ----------------
// wbuf[p*H+h] = alpha for CSR position p, head h
__global__ void k_stats(const int* indptr, const int* srcs, const float* es, const float* ed,
                        float* wbuf, int N){
    int idx = blockIdx.x*blockDim.x+threadIdx.x;
    if(idx >= N*NHEADS) return;
    int n = idx/NHEADS, h = idx%NHEADS;
    int p0 = indptr[n], p1 = indptr[n+1];
    float edv = ed[idx];
    float m = -1e30f;
    for(int p=p0;p<p1;p++){
        float v = es[srcs[p]*NHEADS+h] + edv;
        v = (v>=0.f)? v : 0.2f*v;
        m = fmaxf(m, v);
    }
    float den=0.f;
    for(int p=p0;p<p1;p++){
        float v = es[srcs[p]*NHEADS+h] + edv;
        v = (v>=0.f)? v : 0.2f*v;
        den += expf(v-m);
    }
    float dinv = 1.f/(den+1e-16f);
    for(int p=p0;p<p1;p++){
        float v = es[srcs[p]*NHEADS+h] + edv;
        v = (v>=0.f)? v : 0.2f*v;
        wbuf[(size_t)p*NHEADS+h] = expf(v-m)*dinv;
    }
}

// ---------------- aggregation: out[n,c] = elu(mean_h sum_j alpha*hf[src] + bc) ----------------
template<int C>
__global__ void k_agg(const int* indptr, const int* srcs, const float* wbuf,
                      const float* hf, const float* bc, float* out, int N){
    constexpr int NPB = 256/C;
    int n = blockIdx.x*NPB + threadIdx.x/C;
    int c = threadIdx.x%C;
    if(n>=N) return;
    int p0=indptr[n], p1=indptr[n+1];
    float acc=0.f;
    for(int p=p0;p<p1;p++){
        int s = srcs[p];
        const float* hp = hf + (size_t)s*NHEADS*C + c;
        const float* wp = wbuf + (size_t)p*NHEADS;
        #pragma unroll
        for(int h=0;h<NHEADS;h++){
            acc += wp[h] * hp[h*C];
        }
    }
    float val = acc*(1.f/NHEADS) + bc[c];
    out[n*C+c] = val>0.f? val : expm1f(val);
}

// ---------------- fc1: [N,128]@[128,256]+b, ELU ----------------
__global__ void k_fc1(const float* hin, const float* W1, const float* b1, float* out, int N){
    __shared__ float row[128];
    int n = blockIdx.x;
    int t = threadIdx.x;
    if(t<128) row[t]=hin[n*128+t];
    __syncthreads();
    float acc = b1[t];
    #pragma unroll
    for(int k=0;k<128;k++) acc += row[k]*W1[k*256+t];
    out[n*256+t] = acc>0.f? acc : expm1f(acc);
}

// ---------------- head: logits 256->24 + log_softmax ----------------
__global__ void k_head(const float* hin, const float* W2, const float* b2v, float* out, int N){
    int grp  = threadIdx.x/32;     // 8 groups of 32 per block
    int lane = threadIdx.x%32;
    int n = blockIdx.x*8 + grp;
    if(n>=N) return;
    float acc = -1e30f;
    if(lane < 24){
        acc = b2v[lane];
        for(int k=0;k<256;k++) acc += hin[n*256+k]*W2[k*24+lane];
    }
    float mx = acc;
    for(int off=16; off; off>>=1) mx = fmaxf(mx, __shfl_xor(mx, off, 32));
    float ex = (lane<24)? expf(acc-mx) : 0.f;
    float sm = ex;
    for(int off=16; off; off>>=1) sm += __shfl_xor(sm, off, 32);
    if(lane<24) out[n*24+lane] = acc - mx - logf(sm);
}

extern "C" void kernel_launch(void* const* d_in, const int* in_sizes, int n_in,
                              void* d_out, int out_size, void* d_ws, size_t ws_size,
                              hipStream_t stream) {
    const float* x   = (const float*)d_in[0];
    const int*  eidx = (const int*)d_in[1];
    // d_in[2] = batch (unused by reference output)
    const float* W0 = (const float*)d_in[3];  const float* b0 = (const float*)d_in[4];
    const float* Wc1= (const float*)d_in[5];  const float* as1= (const float*)d_in[6];
    const float* ad1= (const float*)d_in[7];  const float* bc1= (const float*)d_in[8];
    const float* Wc2= (const float*)d_in[9];  const float* as2= (const float*)d_in[10];
    const float* ad2= (const float*)d_in[11]; const float* bc2= (const float*)d_in[12];
    const float* Wc3= (const float*)d_in[13]; const float* as3= (const float*)d_in[14];
    const float* ad3= (const float*)d_in[15]; const float* bc3= (const float*)d_in[16];
    const float* W1 = (const float*)d_in[17]; const float* b1 = (const float*)d_in[18];
    const float* W2 = (const float*)d_in[19]; const float* b2 = (const float*)d_in[20];
    float* out = (float*)d_out;

    const int N  = in_sizes[0]/24;
    const int E  = in_sizes[1]/2;
    const int ET = E + N;

    char* w = (char*)d_ws;
    size_t off = 0;
    auto alloc = [&](size_t bytes)->void* {
        void* p = w + off;
        off = (off + bytes + 255) & ~(size_t)255;
        return p;
    };
    int*   cnt    = (int*)  alloc((size_t)N*4);
    int*   indptr = (int*)  alloc((size_t)(N+1)*4);
    int*   srcs   = (int*)  alloc((size_t)ET*4);
    float* es     = (float*)alloc((size_t)N*NHEADS*4);
    float* ed     = (float*)alloc((size_t)N*NHEADS*4);
    float* wbuf   = (float*)alloc((size_t)ET*NHEADS*4);
    float* nfA    = (float*)alloc((size_t)N*256*4);
    float* nfB    = (float*)alloc((size_t)N*256*4);
    float* hf     = (float*)alloc((size_t)N*1280*4);

    // CSR by dst
    hipMemsetAsync(cnt, 0, (size_t)N*4, stream);
    int gE = (ET+255)/256;
    k_count<<<gE,256,0,stream>>>(eidx, E, N, cnt);
    k_scan <<<1,1024,0,stream>>>(cnt, N, ET, indptr);
    k_fill <<<gE,256,0,stream>>>(eidx, E, N, cnt, srcs);

    int gNH = (N*NHEADS+255)/256;

    // fc0
    k_fc0<<<(N*16+255)/256,256,0,stream>>>(x, W0, b0, nfA, N);

    // GAT1: 16 -> H x 32
    k_feat<16,320><<<N,256,0,stream>>>(nfA, Wc1, hf, N);
    k_attn<32><<<gNH,256,0,stream>>>(hf, as1, ad1, es, ed, N);
    k_stats<<<gNH,256,0,stream>>>(indptr, srcs, es, ed, wbuf, N);
    k_agg<32><<<(N+7)/8,256,0,stream>>>(indptr, srcs, wbuf, hf, bc1, nfB, N);

    // GAT2: 32 -> H x 64
    k_feat<32,640><<<N,256,0,stream>>>(nfB, Wc2, hf, N);
    k_attn<64><<<gNH,256,0,stream>>>(hf, as2, ad2, es, ed, N);
    k_stats<<<gNH,256,0,stream>>>(indptr, srcs, es, ed, wbuf, N);
    k_agg<64><<<(N+3)/4,256,0,stream>>>(indptr, srcs, wbuf, hf, bc2, nfA, N);

    // GAT3: 64 -> H x 128
    k_feat<64,1280><<<N,256,0,stream>>>(nfA, Wc3, hf, N);
    k_attn<128><<<gNH,256,0,stream>>>(hf, as3, ad3, es, ed, N);
    k_stats<<<gNH,256,0,stream>>>(indptr, srcs, es, ed, wbuf, N);
    k_agg<128><<<(N+1)/2,256,0,stream>>>(indptr, srcs, wbuf, hf, bc3, nfB, N);

    // fc1 + head
    k_fc1<<<N,256,0,stream>>>(nfB, W1, b1, nfA, N);
    k_head<<<(N+7)/8,256,0,stream>>>(nfA, W2, b2, out, N);
}